// Round 13
// baseline (76.402 us; speedup 1.0000x reference)
//
#include <hip/hip_runtime.h>
#include <hip/hip_fp16.h>

#define EPS 1e-5f
#define NSLOT 64   // spread-slot copies of the stats accumulators (64 floats each)
#define FLT_BIG 3.402823466e+38f

__device__ __forceinline__ float waveReduceSum(float v) {
    #pragma unroll
    for (int off = 32; off > 0; off >>= 1)
        v += __shfl_down(v, off, 64);
    return v;
}

// Butterfly-compaction reduction: NV stats spread across lanes.
template <int NV>
__device__ __forceinline__ float statReduce(float (&v)[NV], int lane) {
    #pragma unroll
    for (int b = 0; (1 << b) < NV; ++b) {
        const int d = 1 << b;
        const bool hi = (lane >> b) & 1;
        #pragma unroll
        for (int i = 0; i < (NV >> (b + 1)); ++i) {
            float kept = hi ? v[2 * i + 1] : v[2 * i];
            float sent = hi ? v[2 * i] : v[2 * i + 1];
            float recv = __shfl_xor(sent, d, 64);
            v[i] = kept + recv;
        }
    }
    float r = v[0];
    #pragma unroll
    for (int d = NV; d < 64; d <<= 1)
        r += __shfl_xor(r, d, 64);
    return r;
}

__device__ __forceinline__ void unpack8(float4 raw, float* g) {
    const __half2* hp = reinterpret_cast<const __half2*>(&raw);
    #pragma unroll
    for (int q = 0; q < 4; ++q) {
        float2 f = __half22float2(hp[q]);
        g[2 * q] = f.x; g[2 * q + 1] = f.y;
    }
}

__device__ __forceinline__ float4 pack8(const float* g) {
    __half2 hp[4];
    #pragma unroll
    for (int q = 0; q < 4; ++q)
        hp[q] = __floats2half2_rn(g[2 * q], g[2 * q + 1]);
    return *reinterpret_cast<float4*>(hp);
}

// ---------------- K0: zero slots (16 KB) + p1's zeros-row ----------------
__global__ __launch_bounds__(256) void k_zero(float4* __restrict__ slots,
                                              float4* __restrict__ p1zrow) {
    const float4 z4 = {0.f, 0.f, 0.f, 0.f};
    #pragma unroll
    for (int q = 0; q < 4; ++q)
        slots[q * 256 + threadIdx.x] = z4;
    if (threadIdx.x == 0) p1zrow[0] = z4;
}

// ---------------- K1: sparse conv1 (1 -> 8), fp16 x1 rows (16 B), BN1-stat partials ----------------
__global__ __launch_bounds__(256, 4) void k_conv1(
        const float* __restrict__ f0, const float* __restrict__ W1,
        const float* __restrict__ b1, const int* __restrict__ nbr0,
        float4* __restrict__ x1h, float* __restrict__ slots, int n0) {
    __shared__ float sred[16];
    int t = threadIdx.x;
    int lane = t & 63;
    if (t < 16) sred[t] = 0.f;
    __syncthreads();

    int n = blockIdx.x * blockDim.x + t;
    bool valid = (n < n0);
    int nn = valid ? n : (n0 - 1);

    int idx[9];
    #pragma unroll
    for (int k = 0; k < 9; ++k) idx[k] = nbr0[(size_t)nn * 9 + k];
    float v[9];
    #pragma unroll
    for (int k = 0; k < 9; ++k) {
        float f = f0[idx[k] >= 0 ? idx[k] : 0];
        v[k] = (idx[k] >= 0) ? f : 0.f;
    }

    float acc[8];
    #pragma unroll
    for (int c = 0; c < 8; ++c) acc[c] = b1[c];
    #pragma unroll
    for (int k = 0; k < 9; ++k)
        #pragma unroll
        for (int c = 0; c < 8; ++c) acc[c] = fmaf(v[k], W1[k * 8 + c], acc[c]);

    if (valid) x1h[n] = pack8(acc);
    else {
        #pragma unroll
        for (int c = 0; c < 8; ++c) acc[c] = 0.f;
    }

    float red[16];
    #pragma unroll
    for (int c = 0; c < 8; ++c) {
        red[c] = acc[c];
        red[8 + c] = acc[c] * acc[c];
    }
    float tot = statReduce<16>(red, lane);
    if (lane < 16) atomicAdd(&sred[lane], tot);
    __syncthreads();
    if (t < 16)
        atomicAdd(&slots[(size_t)(blockIdx.x & (NSLOT - 1)) * 64 + t], sred[t]);
}

// ---------------- K1b: finalize BN1 -> folded consts (sc1, b01) in stats[0:16) ----------------
__global__ __launch_bounds__(64) void k_bn1stats(
        const float* __restrict__ slots, const float* __restrict__ gamma1,
        const float* __restrict__ beta1, float* __restrict__ stats, float invn0) {
    __shared__ float st[16];
    int t = threadIdx.x;
    if (t < 16) {
        float s = 0.f;
        #pragma unroll 8
        for (int k = 0; k < NSLOT; ++k) s += slots[(size_t)k * 64 + t];
        st[t] = s;
    }
    __syncthreads();
    if (t < 8) {
        float mu  = st[t] * invn0;
        float var = st[8 + t] * invn0 - mu * mu;
        float sc  = rsqrtf(var + EPS) * gamma1[t];
        stats[t]     = sc;
        stats[8 + t] = beta1[t] - sc * mu;
    }
}

// ---------------- K2: BN1+ReLU (folded) fused into 2x2 max pool; fp16 p1 rows ----------------
__global__ __launch_bounds__(256, 4) void k_pool1(
        const float4* __restrict__ x1h, const int* __restrict__ pmap1,
        const float* __restrict__ stats, float4* __restrict__ p1h, int n1) {
    int i = blockIdx.x * blockDim.x + threadIdx.x;
    if (i >= n1) return;

    int4 pm = ((const int4*)pmap1)[i];
    int idx[4] = {pm.x, pm.y, pm.z, pm.w};
    float best[8];
    #pragma unroll
    for (int c = 0; c < 8; ++c) best[c] = 0.f;
    #pragma unroll
    for (int k = 0; k < 4; ++k) {
        float4 raw = x1h[idx[k] >= 0 ? idx[k] : 0];
        float v[8];
        unpack8(raw, v);
        #pragma unroll
        for (int c = 0; c < 8; ++c) {
            float z = fmaxf(fmaf(v[c], stats[c], stats[8 + c]), 0.f);
            z = (idx[k] >= 0) ? z : 0.f;
            best[c] = fmaxf(best[c], z);
        }
    }
    p1h[i] = pack8(best);
}

// ---------------- K3: conv2 (8->16) one CHILD per lane; pool across the 4 child
// lanes in-register (max if gamma2>=0 else min — BN2 monotone); BN2-stat partials.
// No x2 buffer: writes only pooled raw extrema pm2 (16 f32/site).
__global__ __launch_bounds__(256, 4) void k_conv2pool(
        const float4* __restrict__ p1h, const float* __restrict__ W2,
        const float* __restrict__ b2, const int* __restrict__ nbr1,
        const int* __restrict__ pmap2, const float* __restrict__ gamma2,
        float* __restrict__ pm2, float* __restrict__ slots,
        int n1, int n2, int nblk) {
    __shared__ float sred[32];
    int t = threadIdx.x;
    int lane = t & 63;
    if (t < 32) sred[t] = 0.f;
    __syncthreads();

    // bijective XCD swizzle (m204): blocks with equal (blockIdx%8) -> one XCD get
    // a contiguous chunk of sites -> each XCD's L2 serves a contiguous p1h window.
    int wg  = blockIdx.x;
    int q   = nblk >> 3, r = nblk & 7;
    int xcd = wg & 7, off = wg >> 3;
    int swz = (xcd < r ? xcd * (q + 1) : r * (q + 1) + (xcd - r) * q) + off;

    int gt   = swz * 256 + t;
    int site = gt >> 2;          // level-2 site
    int ck   = gt & 3;           // child slot 0..3
    bool sv  = (site < n2);
    int scl  = sv ? site : (n2 - 1);
    int child = pmap2[(size_t)scl * 4 + ck];
    bool cv  = sv && (child >= 0);
    int row  = cv ? child : 0;

    int idx[9];
    #pragma unroll
    for (int k = 0; k < 9; ++k) {
        int j = nbr1[(size_t)row * 9 + k];
        idx[k] = (j >= 0) ? j : n1;          // zeros-row
    }

    float acc[16];
    #pragma unroll
    for (int c = 0; c < 16; ++c) acc[c] = b2[c];

    #pragma unroll
    for (int k = 0; k < 9; ++k) {
        float4 raw = p1h[idx[k]];
        float g[8];
        unpack8(raw, g);
        #pragma unroll
        for (int ci = 0; ci < 8; ++ci) {
            #pragma unroll
            for (int c = 0; c < 16; ++c)
                acc[c] = fmaf(g[ci], W2[(k * 8 + ci) * 16 + c], acc[c]);
        }
    }

    // BN2 stats over valid children == all level-1 points exactly once
    float red[32];
    #pragma unroll
    for (int c = 0; c < 16; ++c) {
        float a = cv ? acc[c] : 0.f;
        red[c] = a;
        red[16 + c] = a * a;
    }
    float tot = statReduce<32>(red, lane);
    if (lane < 32) atomicAdd(&sred[lane], tot);

    // pool across child lanes (xor 1, xor 2) with per-channel max/min select
    float pv[16];
    #pragma unroll
    for (int c = 0; c < 16; ++c) {
        bool gp = (gamma2[c] >= 0.f);
        float v = cv ? acc[c] : (gp ? -FLT_BIG : FLT_BIG);
        float m1 = __shfl_xor(v, 1, 64);
        v = gp ? fmaxf(v, m1) : fminf(v, m1);
        float m2 = __shfl_xor(v, 2, 64);
        v = gp ? fmaxf(v, m2) : fminf(v, m2);
        pv[c] = v;
    }
    if (sv && ck == 0) {
        float4* dst = (float4*)(pm2 + (size_t)site * 16);
        #pragma unroll
        for (int q4 = 0; q4 < 4; ++q4)
            dst[q4] = make_float4(pv[q4 * 4], pv[q4 * 4 + 1],
                                  pv[q4 * 4 + 2], pv[q4 * 4 + 3]);
    }

    __syncthreads();
    if (t < 32)
        atomicAdd(&slots[(size_t)(blockIdx.x & (NSLOT - 1)) * 64 + 16 + t], sred[t]);
}

// ---------------- K3b: finalize BN2 -> folded consts (sc2, b02) in stats[16:48) ----------------
__global__ __launch_bounds__(64) void k_bn2stats(
        const float* __restrict__ slots, const float* __restrict__ gamma2,
        const float* __restrict__ beta2, float* __restrict__ stats, float invn1) {
    __shared__ float st[32];
    int t = threadIdx.x;
    if (t < 32) {
        float s = 0.f;
        #pragma unroll 8
        for (int k = 0; k < NSLOT; ++k) s += slots[(size_t)k * 64 + 16 + t];
        st[t] = s;
    }
    __syncthreads();
    if (t < 16) {
        float mu  = st[t] * invn1;
        float var = st[16 + t] * invn1 - mu * mu;
        float sc  = rsqrtf(var + EPS) * gamma2[t];
        stats[16 + t] = sc;
        stats[32 + t] = beta2[t] - sc * mu;
    }
}

// ---------------- K4: BN2-affine + ReLU + FC(16->2) from pooled raw extrema ----------------
__global__ __launch_bounds__(256) void k_bn2fc(
        const float* __restrict__ pm2, const float* __restrict__ stats,
        const float* __restrict__ Wfc, const float* __restrict__ bfc,
        float* __restrict__ out, int n2) {
    int i = blockIdx.x * blockDim.x + threadIdx.x;
    if (i >= n2) return;
    const float4* src = (const float4*)(pm2 + (size_t)i * 16);
    float o0 = bfc[0], o1 = bfc[1];
    #pragma unroll
    for (int q4 = 0; q4 < 4; ++q4) {
        float4 v4 = src[q4];
        float v[4] = {v4.x, v4.y, v4.z, v4.w};
        #pragma unroll
        for (int c = 0; c < 4; ++c) {
            int cc = q4 * 4 + c;
            float z = fmaxf(fmaf(v[c], stats[16 + cc], stats[32 + cc]), 0.f);
            o0 = fmaf(z, Wfc[cc * 2 + 0], o0);
            o1 = fmaf(z, Wfc[cc * 2 + 1], o1);
        }
    }
    out[(size_t)i * 2 + 0] = o0;
    out[(size_t)i * 2 + 1] = o1;
}

extern "C" void kernel_launch(void* const* d_in, const int* in_sizes, int n_in,
                              void* d_out, int out_size, void* d_ws, size_t ws_size,
                              hipStream_t stream) {
    const float* f0     = (const float*)d_in[0];
    const float* W1     = (const float*)d_in[1];
    const float* b1     = (const float*)d_in[2];
    const float* gamma1 = (const float*)d_in[3];
    const float* beta1  = (const float*)d_in[4];
    const float* W2     = (const float*)d_in[5];
    const float* b2     = (const float*)d_in[6];
    const float* gamma2 = (const float*)d_in[7];
    const float* beta2  = (const float*)d_in[8];
    const float* Wfc    = (const float*)d_in[9];
    const float* bfc    = (const float*)d_in[10];
    const int*   nbr0   = (const int*)d_in[11];
    const int*   pmap1  = (const int*)d_in[12];
    const int*   nbr1   = (const int*)d_in[13];
    const int*   pmap2  = (const int*)d_in[14];

    const int n0 = in_sizes[0];
    const int n1 = in_sizes[12] / 4;
    const int n2 = in_sizes[14] / 4;

    float*  ws    = (float*)d_ws;
    float*  slots = ws;                                  // NSLOT*64 f32 (16 KB)
    float*  stats = ws + (size_t)NSLOT * 64;             // 64 f32 (sc1,b01,sc2,b02)
    float4* x1h   = (float4*)(stats + 64);               // n0 rows   x 16 B (fp16x8)
    float4* p1h   = x1h + n0;                            // n1+1 rows x 16 B (row n1 = zeros)
    float*  pm2   = (float*)(p1h + n1 + 1);              // n2*16 f32 pooled raw extrema

    const int B = 256;
    const int nblk2 = (n2 * 4 + B - 1) / B;
    k_zero<<<1, B, 0, stream>>>((float4*)slots, p1h + n1);
    k_conv1<<<(n0 + B - 1) / B, B, 0, stream>>>(f0, W1, b1, nbr0, x1h, slots, n0);
    k_bn1stats<<<1, 64, 0, stream>>>(slots, gamma1, beta1, stats, 1.0f / (float)n0);
    k_pool1<<<(n1 + B - 1) / B, B, 0, stream>>>(x1h, pmap1, stats, p1h, n1);
    k_conv2pool<<<nblk2, B, 0, stream>>>(p1h, W2, b2, nbr1, pmap2, gamma2,
                                         pm2, slots, n1, n2, nblk2);
    k_bn2stats<<<1, 64, 0, stream>>>(slots, gamma2, beta2, stats, 1.0f / (float)n1);
    k_bn2fc<<<(n2 + B - 1) / B, B, 0, stream>>>(pm2, stats, Wfc, bfc,
                                                (float*)d_out, n2);
}